// Round 7
// baseline (430.594 us; speedup 1.0000x reference)
//
#include <hip/hip_runtime.h>
#include <math.h>
#include <float.h>

#define N_ROWS 131072
#define DIM 64
#define KM1 1023
#define KPAD 1024

// ---- ws layout (bytes) ----
#define DT_OFF   0         // float[64][1024] transposed, pre-doubled dith
#define D2_OFF   262144    // float[1024]
#define CNT_OFF  266240    // u32[1024]
#define IDX_OFF  270336    // i32[131072]

// Opacity guard: stops ffp-contract=fast from changing rounding vs numpy.
#define OPQ(x) asm volatile("" : "+v"(x))

__device__ __forceinline__ float lerp_exact(float lo, float hi, float tt) {
    float hl = __fsub_rn(hi, lo);
    float p  = __fmul_rn(tt, hl);
    OPQ(p);
    float dv = __fadd_rn(lo, p);
    OPQ(dv);
    return dv;
}

typedef __attribute__((address_space(3))) void lds_void;
typedef __attribute__((address_space(1))) const void glob_void;

// Column swizzle within a 128-col dT row: involution c -> c ^ ((c>>5)<<2).
// Spreads the 4 32-col groups across distinct bank-quads; quads (4 cols,
// 4-aligned) stay contiguous so b128 reads still work.
__device__ __forceinline__ int dswz(int c) {
    return c ^ (((c >> 5) & 3) << 2);
}

// Kernel A: dither + transpose (pre-doubled) + d2 (numpy pairwise) + zero counts.
__global__ void __launch_bounds__(256)
prep_kernel(const float* __restrict__ cb, const float* __restrict__ dither,
            float* __restrict__ dithT, float* __restrict__ d2,
            unsigned* __restrict__ counts) {
    __shared__ float S[64 * 65];
    const int t = threadIdx.x, b = blockIdx.x;
    const int gt = b * 256 + t;
    if (gt < 1024) counts[gt] = 0u;
    const int kl = t >> 2, c = t & 3;
    const int k = b * 64 + kl;
    float* Sw = S + kl * 65 + 16 * c;
    if (k < KM1) {
        float tt = dither[k];
        const float4* lo4 = (const float4*)(cb + (size_t)k * 64 + 16 * c);
        const float4* hi4 = (const float4*)(cb + (size_t)(k + 1) * 64 + 16 * c);
        #pragma unroll
        for (int q = 0; q < 4; ++q) {
            float4 lo = lo4[q], hi = hi4[q];
            Sw[4 * q + 0] = lerp_exact(lo.x, hi.x, tt);
            Sw[4 * q + 1] = lerp_exact(lo.y, hi.y, tt);
            Sw[4 * q + 2] = lerp_exact(lo.z, hi.z, tt);
            Sw[4 * q + 3] = lerp_exact(lo.w, hi.w, tt);
        }
    } else {
        #pragma unroll
        for (int q = 0; q < 16; ++q) Sw[q] = 0.f;
    }
    __syncthreads();
    if (t < 64) {
        const float* Sr = S + t * 65;
        float r[8];
        #pragma unroll
        for (int j = 0; j < 8; ++j) {
            float x = Sr[j]; float bb = __fmul_rn(x, x); OPQ(bb); r[j] = bb;
        }
        #pragma unroll
        for (int i = 8; i < 64; i += 8) {
            #pragma unroll
            for (int j = 0; j < 8; ++j) {
                float x = Sr[i + j]; float bb = __fmul_rn(x, x); OPQ(bb);
                r[j] = __fadd_rn(r[j], bb);
            }
        }
        float s = __fadd_rn(
            __fadd_rn(__fadd_rn(r[0], r[1]), __fadd_rn(r[2], r[3])),
            __fadd_rn(__fadd_rn(r[4], r[5]), __fadd_rn(r[6], r[7])));
        int kk = b * 64 + t;
        d2[kk] = (kk >= KM1) ? FLT_MAX : s;
    }
    {
        const int i = t >> 2;
        float v[16];
        #pragma unroll
        for (int j = 0; j < 16; ++j) {
            float x = S[(16 * c + j) * 65 + i];
            v[j] = __fadd_rn(x, x);            // exact 2x
        }
        float4* dst = (float4*)(dithT + (size_t)i * KPAD + b * 64 + 16 * c);
        dst[0] = make_float4(v[0], v[1], v[2], v[3]);
        dst[1] = make_float4(v[4], v[5], v[6], v[7]);
        dst[2] = make_float4(v[8], v[9], v[10], v[11]);
        dst[3] = make_float4(v[12], v[13], v[14], v[15]);
    }
}

// Kernel B: argmin. Block = 256 rows x 1023 k (8 tiles of 128 k).
// 4 waves = 4 row-quarters (each wave sees ALL k for its 64 rows -> no
// cross-wave merge). Lane = (rg 0..7, kg 0..7); micro-tile 8 rows x 16 k
// (128 acc). dT double-buffered, column-XOR-swizzled, staged via
// global_load_lds with pre-swizzled global source. Bit-exact numpy scoring.
__global__ void __launch_bounds__(256, 1)
argmin_kernel(const float* __restrict__ z_g,
              const float* __restrict__ dithT,
              const float* __restrict__ d2g,
              int* __restrict__ idx_out) {
    __shared__ float zT[64][256];          // [dim][row]          64 KB
    __shared__ float dTl[2][64 * 128];     // [dim][swz col] x2   64 KB
    __shared__ float zsArr[256];
    const int tid  = threadIdx.x;
    const int w    = tid >> 6;
    const int lane = tid & 63;
    const int rg   = lane >> 3;            // 0..7
    const int kg   = lane & 7;             // 0..7
    const int rowbase = blockIdx.x << 8;
    const int R0 = (w << 6) + (rg << 3);   // lane's first row within block

    // Stage zT transposed (one-time): thread = row.
    {
        const float4* src = (const float4*)(z_g + ((size_t)(rowbase + tid) << 6));
        #pragma unroll
        for (int q = 0; q < 16; ++q) {
            float4 v = src[q];
            zT[4 * q + 0][tid] = v.x;
            zT[4 * q + 1][tid] = v.y;
            zT[4 * q + 2][tid] = v.z;
            zT[4 * q + 3][tid] = v.w;
        }
    }

    // Issue tile-0 stage: 32 chunks of 1 KB; wave w does chunks 8w..8w+7.
    // Chunk q -> dims {2q, 2q+1}; lane writes LDS linearly at (lane&31)*4,
    // loads global from the swizzle-inverse column (involution).
    const int o_pos = (lane & 31) << 2;
    const int o_src = dswz(o_pos);
    #pragma unroll
    for (int j = 0; j < 8; ++j) {
        const int q = 8 * w + j;
        const int dim = 2 * q + (lane >> 5);
        const float* gp = dithT + ((size_t)dim << 10) + o_src;
        __builtin_amdgcn_global_load_lds((glob_void*)gp,
                                         (lds_void*)(&dTl[0][q << 8]), 16, 0, 0);
    }
    __syncthreads();   // zT + tile0 ready

    // Fused zsum: thread r computes numpy-pairwise sum of fl(z^2) from zT.
    {
        float acc8[8];
        #pragma unroll
        for (int m = 0; m < 8; ++m) {
            #pragma unroll
            for (int j = 0; j < 8; ++j) {
                float x = zT[8 * m + j][tid];
                float sq = __fmul_rn(x, x); OPQ(sq);
                acc8[j] = (m == 0) ? sq : __fadd_rn(acc8[j], sq);
            }
        }
        zsArr[tid] = __fadd_rn(
            __fadd_rn(__fadd_rn(acc8[0], acc8[1]), __fadd_rn(acc8[2], acc8[3])),
            __fadd_rn(__fadd_rn(acc8[4], acc8[5]), __fadd_rn(acc8[6], acc8[7])));
    }
    __syncthreads();

    float zs8[8];
    #pragma unroll
    for (int r = 0; r < 8; ++r) zs8[r] = zsArr[R0 + r];

    // Swizzled read offsets for this lane's 4 d-quads (cols kg*16 + 4m).
    int dq0, dq1, dq2, dq3;
    dq0 = dswz((kg << 4) + 0);
    dq1 = dswz((kg << 4) + 4);
    dq2 = dswz((kg << 4) + 8);
    dq3 = dswz((kg << 4) + 12);

    float b[8]; int bi[8];
    #pragma unroll
    for (int r = 0; r < 8; ++r) { b[r] = FLT_MAX; bi[r] = 0; }

    const float* zrow = &zT[0][R0];
    int cur = 0;

    #pragma unroll 1
    for (int t = 0; t < 8; ++t) {
        if (t < 7) {   // stage tile t+1 into the other buffer (hidden by compute)
            #pragma unroll
            for (int j = 0; j < 8; ++j) {
                const int q = 8 * w + j;
                const int dim = 2 * q + (lane >> 5);
                const float* gp = dithT + ((size_t)dim << 10)
                                  + ((t + 1) << 7) + o_src;
                __builtin_amdgcn_global_load_lds(
                    (glob_void*)gp, (lds_void*)(&dTl[cur ^ 1][q << 8]), 16, 0, 0);
            }
        }
        const int kb = (t << 7) + (kg << 4);   // lane's first global k this tile
        const float4 e0 = *(const float4*)(d2g + kb);
        const float4 e1 = *(const float4*)(d2g + kb + 4);
        const float4 e2 = *(const float4*)(d2g + kb + 8);
        const float4 e3 = *(const float4*)(d2g + kb + 12);

        float acc[8][16];
        #pragma unroll
        for (int r = 0; r < 8; ++r) {
            #pragma unroll
            for (int k = 0; k < 16; ++k) acc[r][k] = 0.f;
        }
        const float* dc = dTl[cur];
        #pragma unroll 2
        for (int i = 0; i < 64; ++i) {
            const float4 z0 = *(const float4*)(zrow + i * 256);
            const float4 z1 = *(const float4*)(zrow + i * 256 + 4);
            const float4 d0 = *(const float4*)(dc + i * 128 + dq0);
            const float4 d1 = *(const float4*)(dc + i * 128 + dq1);
            const float4 d2v = *(const float4*)(dc + i * 128 + dq2);
            const float4 d3 = *(const float4*)(dc + i * 128 + dq3);
            const float zz[8] = {z0.x, z0.y, z0.z, z0.w, z1.x, z1.y, z1.z, z1.w};
            const float dd[16] = {d0.x, d0.y, d0.z, d0.w, d1.x, d1.y, d1.z, d1.w,
                                  d2v.x, d2v.y, d2v.z, d2v.w, d3.x, d3.y, d3.z, d3.w};
            #pragma unroll
            for (int r = 0; r < 8; ++r) {
                #pragma unroll
                for (int k = 0; k < 16; ++k)
                    acc[r][k] = fmaf(zz[r], dd[k], acc[r][k]);
            }
        }
        const float ee[16] = {e0.x, e0.y, e0.z, e0.w, e1.x, e1.y, e1.z, e1.w,
                              e2.x, e2.y, e2.z, e2.w, e3.x, e3.y, e3.z, e3.w};
        #pragma unroll
        for (int r = 0; r < 8; ++r) {
            #pragma unroll
            for (int k = 0; k < 16; ++k) {
                float D = __fsub_rn(__fadd_rn(zs8[r], ee[k]), acc[r][k]);
                if (D < b[r]) { b[r] = D; bi[r] = kb + k; }
            }
        }
        __syncthreads();   // all reads of dTl[cur] done; staged tile landed
        cur ^= 1;
    }

    // kg-octet merge (ties -> smaller k), then direct store (wave owns rows).
    #pragma unroll
    for (int d = 1; d <= 4; d <<= 1) {
        #pragma unroll
        for (int r = 0; r < 8; ++r) {
            float ov = __shfl_xor(b[r], d);
            int   ok = __shfl_xor(bi[r], d);
            if (ov < b[r] || (ov == b[r] && ok < bi[r])) { b[r] = ov; bi[r] = ok; }
        }
    }
    if (kg == 0) {
        #pragma unroll
        for (int r = 0; r < 8; ++r)
            idx_out[rowbase + R0 + r] = bi[r];
    }
}

// Kernel C: per-row finalize. One wave per row (lane = dim).
__global__ void __launch_bounds__(256)
finalize_kernel(const float* __restrict__ z_g,
                const float* __restrict__ cb,
                const float* __restrict__ dither,
                const float* __restrict__ n1_g,
                const float* __restrict__ n2_g,
                const int* __restrict__ idx_arr,
                float* __restrict__ zq_out,
                float* __restrict__ idxf_out,
                unsigned* __restrict__ counts) {
    int wid = (blockIdx.x * 256 + threadIdx.x) >> 6;
    int lane = threadIdx.x & 63;
    int idx = idx_arr[wid];
    size_t base = (size_t)wid * DIM + lane;
    float z  = z_g[base];
    float n1 = n1_g[base];
    float n2 = n2_g[base];
    float c1 = cb[idx * DIM + lane];
    float c2 = cb[(idx + 1) * DIM + lane];
    float lam = dither[idx];
    float d1 = c1 - z, d2v = c2 - z;
    float r1 = n1 + d1, r2 = n2 + d2v;
    float s_r1 = r1 * r1, s_r2 = r2 * r2, s_d1 = d1 * d1, s_d2 = d2v * d2v;
    #pragma unroll
    for (int m = 32; m; m >>= 1) {
        s_r1 += __shfl_xor(s_r1, m, 64);
        s_r2 += __shfl_xor(s_r2, m, 64);
        s_d1 += __shfl_xor(s_d1, m, 64);
        s_d2 += __shfl_xor(s_d2, m, 64);
    }
    float em1 = sqrtf(s_d1), em2 = sqrtf(s_d2);
    float nr1 = fmaxf(sqrtf(s_r1), 1e-12f);
    float nr2 = fmaxf(sqrtf(s_r2), 1e-12f);
    float zq = z + em1 * (1.f - lam) * (r1 / nr1) + em2 * lam * (r2 / nr2);
    zq_out[base] = zq;
    if (lane == 0) {
        idxf_out[wid] = (float)idx;
        atomicAdd(&counts[idx], 1u);
    }
}

// Kernel D: perplexity from counts.
__global__ void ppl_kernel(const unsigned* __restrict__ counts,
                           float* __restrict__ out) {
    __shared__ float partial[16];
    int t = threadIdx.x;
    float p = (float)counts[t] * (1.f / (float)N_ROWS);
    float v = (p > 0.f) ? p * logf(p) : 0.f;
    #pragma unroll
    for (int m = 32; m; m >>= 1) v += __shfl_xor(v, m, 64);
    if ((t & 63) == 0) partial[t >> 6] = v;
    __syncthreads();
    if (t < 16) {
        float s = partial[t];
        #pragma unroll
        for (int m = 8; m; m >>= 1) s += __shfl_xor(s, m, 16);
        if (t == 0) out[0] = expf(-s);
    }
}

extern "C" void kernel_launch(void* const* d_in, const int* in_sizes, int n_in,
                              void* d_out, int out_size, void* d_ws, size_t ws_size,
                              hipStream_t stream) {
    const float* z      = (const float*)d_in[0];
    const float* cb     = (const float*)d_in[1];
    const float* dither = (const float*)d_in[2];
    const float* n1     = (const float*)d_in[3];
    const float* n2     = (const float*)d_in[4];

    char* ws = (char*)d_ws;
    float*    dithT  = (float*)(ws + DT_OFF);
    float*    d2     = (float*)(ws + D2_OFF);
    unsigned* counts = (unsigned*)(ws + CNT_OFF);
    int*      idxa   = (int*)(ws + IDX_OFF);

    float* out  = (float*)d_out;
    float* zq   = out;
    float* idxf = out + (size_t)N_ROWS * DIM;
    float* ppl  = idxf + N_ROWS;

    prep_kernel<<<16, 256, 0, stream>>>(cb, dither, dithT, d2, counts);
    argmin_kernel<<<N_ROWS / 256, 256, 0, stream>>>(z, dithT, d2, idxa);
    finalize_kernel<<<N_ROWS / 4, 256, 0, stream>>>(z, cb, dither, n1, n2,
                                                    idxa, zq, idxf, counts);
    ppl_kernel<<<1, 1024, 0, stream>>>(counts, ppl);
}